// Round 1
// 245.990 us; speedup vs baseline: 1.0746x; 1.0746x over previous
//
#include <hip/hip_runtime.h>

typedef unsigned short u16;
typedef __attribute__((ext_vector_type(8))) short bf16x8;   // 8 bf16 in 4 VGPRs
typedef __attribute__((ext_vector_type(4))) float f32x4;
typedef __attribute__((ext_vector_type(4))) unsigned int u32x4;

#define DIM 2048

__device__ inline u16 f2bf(float f) {
    unsigned u = __builtin_bit_cast(unsigned, f);
    u = (u + 0x7FFFu + ((u >> 16) & 1u)) >> 16;   // RNE, finite inputs only
    return (u16)u;
}

__device__ inline void gl_lds16(const void* g, void* l) {
    __builtin_amdgcn_global_load_lds(
        (const __attribute__((address_space(1))) unsigned int*)g,
        (__attribute__((address_space(3))) unsigned int*)l, 16, 0, 0);
}

struct c32 { float x, y; };
__device__ inline c32 cmul(c32 a, c32 b) { return {a.x*b.x - a.y*b.y, a.x*b.y + a.y*b.x}; }
__device__ inline float2 cmulf2(float2 a, float2 b) {
    return make_float2(a.x*b.x - a.y*b.y, a.x*b.y + a.y*b.x);
}

__device__ inline int slot2(int i) { return i + (i >> 4); }   // float2 bank-pad

// complex butterfly: (u,w) <- (g0*u + g1*w, g2*u + g3*w)
__device__ inline void bfly(float2 g0, float2 g1, float2 g2, float2 g3,
                            float2& u, float2& w) {
    float2 nu, nw;
    nu.x = g0.x*u.x - g0.y*u.y + g1.x*w.x - g1.y*w.y;
    nu.y = g0.x*u.y + g0.y*u.x + g1.x*w.y + g1.y*w.x;
    nw.x = g2.x*u.x - g2.y*u.y + g3.x*w.x - g3.y*w.y;
    nw.y = g2.x*u.y + g2.y*u.x + g3.x*w.y + g3.y*w.x;
    u = nu; w = nw;
}

// ---------------------------------------------------------------------------
// Kernel 1: build T = U^T, one column per block, statevector in LDS (float2).
// Round-14 structure:
//  - Layer 0 is a direct Kronecker product: V[e] = prod_q g[q][e_bit(10-q)][col_bit(10-q)]
//    (basis vector through a tensor-product layer), replacing 4 butterfly rounds.
//  - Ring perm closed form: jj = (i ^ (i>>1)) ^ ((i&1) ? 0x600 : 0)
//    (unrolled CNOT cascade c=10..0), replacing the 11-step sequential loop.
//  - Layers 1..4: register-blocked rounds over bit-triples {10,9,8},{7,6,5},
//    {4,3,2},{1,0}; ring perm absorbed into round A via ptab (validated r6-r13).
// ---------------------------------------------------------------------------
__global__ __launch_bounds__(256) void build_ut(const float* __restrict__ w,
                                                u16* __restrict__ ut_re,
                                                u16* __restrict__ ut_im) {
    __shared__ alignas(16) float2 gg[55][4];          // 2x2 gates, row-major
    __shared__ alignas(16) u16 ptab[DIM];             // slot2(perm(e)), by e
    __shared__ alignas(16) float2 V[DIM + (DIM >> 4)];
    const int tid = threadIdx.x;
    const int col = blockIdx.x;

    if (tid < 55) {
        const int layer = tid / 11, q = tid - layer * 11;
        const float WM = 0.63245553203367586f;   // sqrt(2)*5^-0.5
        float hx = 0.5f * WM * w[33*layer + q];
        float hy = 0.5f * WM * w[33*layer + 11 + q];
        float hz = 0.5f * WM * w[33*layer + 22 + q];
        float cx = cosf(hx), sx = sinf(hx);
        float cy = cosf(hy), sy = sinf(hy);
        float cz = cosf(hz), sz = sinf(hz);
        c32 m00{cy*cx,  sy*sx}, m01{-sy*cx, -cy*sx};
        c32 m10{sy*cx, -cy*sx}, m11{ cy*cx, -sy*sx};
        c32 em{cz, -sz}, ep{cz, sz};
        c32 r0 = cmul(em, m00), r1 = cmul(em, m01);
        c32 r2 = cmul(ep, m10), r3 = cmul(ep, m11);
        gg[tid][0] = make_float2(r0.x, r0.y);
        gg[tid][1] = make_float2(r1.x, r1.y);
        gg[tid][2] = make_float2(r2.x, r2.y);
        gg[tid][3] = make_float2(r3.x, r3.y);
    }
    // ring perm, closed form (unrolled CNOT cascade, c = 10..0):
    //   bits 0..8: b_k ^ b_{k+1};  bit 9: b9^b10^b0;  bit 10: b10^b0
    for (int i = tid; i < DIM; i += 256) {
        int jj = (i ^ (i >> 1)) ^ ((i & 1) ? 0x600 : 0);
        ptab[i] = (u16)slot2(jj);
    }
    __syncthreads();

    // --- Layer 0: direct Kronecker product of a basis vector -------------
    // element e = tid*8 + j; qubit q acts on bit 10-q (MSB-first).
    {
        // prefix over bits 10..3 (qubits 0..7): e's bit b = tid's bit (b-3)
        float2 p = gg[0][((((tid >> 7) & 1) << 1)) | ((col >> 10) & 1)];
        #pragma unroll
        for (int b = 9; b >= 3; --b) {
            float2 ge = gg[10 - b][(((tid >> (b - 3)) & 1) << 1) | ((col >> b) & 1)];
            p = cmulf2(p, ge);
        }
        const int c2 = (col >> 2) & 1, c1 = (col >> 1) & 1, c0 = col & 1;
        float2 a0  = cmulf2(p, gg[8][c2]);       // bit2 = 0
        float2 a1  = cmulf2(p, gg[8][2 | c2]);   // bit2 = 1
        float2 b00 = cmulf2(a0, gg[9][c1]);
        float2 b01 = cmulf2(a0, gg[9][2 | c1]);
        float2 b10 = cmulf2(a1, gg[9][c1]);
        float2 b11 = cmulf2(a1, gg[9][2 | c1]);
        float2 g0 = gg[10][c0], g1 = gg[10][2 | c0];
        const int base = tid << 3;
        V[slot2(base + 0)] = cmulf2(b00, g0);
        V[slot2(base + 1)] = cmulf2(b00, g1);
        V[slot2(base + 2)] = cmulf2(b01, g0);
        V[slot2(base + 3)] = cmulf2(b01, g1);
        V[slot2(base + 4)] = cmulf2(b10, g0);
        V[slot2(base + 5)] = cmulf2(b10, g1);
        V[slot2(base + 6)] = cmulf2(b11, g0);
        V[slot2(base + 7)] = cmulf2(b11, g1);
    }
    __syncthreads();

    // 3-bit round: bits b2>b1>b0, gates gq2 on b2, gq1 on b1, gq0 on b0.
    auto round3 = [&](int b2, int b1, int b0, int gq2, int gq1, int gq0,
                      bool permRead) {
        int x = tid;
        x = ((x >> b0) << (b0 + 1)) | (x & ((1 << b0) - 1));
        x = ((x >> b1) << (b1 + 1)) | (x & ((1 << b1) - 1));
        x = ((x >> b2) << (b2 + 1)) | (x & ((1 << b2) - 1));
        float2 v[8]; int sl[8];
        #pragma unroll
        for (int j = 0; j < 8; ++j) {
            int e = x | ((j >> 2) << b2) | (((j >> 1) & 1) << b1) | ((j & 1) << b0);
            sl[j] = slot2(e);
            v[j] = V[permRead ? (int)ptab[e] : sl[j]];
        }
        if (permRead) __syncthreads();
        {   float2 g0 = gg[gq2][0], g1 = gg[gq2][1], g2 = gg[gq2][2], g3 = gg[gq2][3];
            bfly(g0,g1,g2,g3, v[0], v[4]); bfly(g0,g1,g2,g3, v[1], v[5]);
            bfly(g0,g1,g2,g3, v[2], v[6]); bfly(g0,g1,g2,g3, v[3], v[7]); }
        {   float2 g0 = gg[gq1][0], g1 = gg[gq1][1], g2 = gg[gq1][2], g3 = gg[gq1][3];
            bfly(g0,g1,g2,g3, v[0], v[2]); bfly(g0,g1,g2,g3, v[1], v[3]);
            bfly(g0,g1,g2,g3, v[4], v[6]); bfly(g0,g1,g2,g3, v[5], v[7]); }
        {   float2 g0 = gg[gq0][0], g1 = gg[gq0][1], g2 = gg[gq0][2], g3 = gg[gq0][3];
            bfly(g0,g1,g2,g3, v[0], v[1]); bfly(g0,g1,g2,g3, v[2], v[3]);
            bfly(g0,g1,g2,g3, v[4], v[5]); bfly(g0,g1,g2,g3, v[6], v[7]); }
        #pragma unroll
        for (int j = 0; j < 8; ++j) V[sl[j]] = v[j];
        __syncthreads();
    };

    // 2-bit round: bits {1,0}, gates gq1 on bit1, gq0 on bit0. In-place.
    auto round2 = [&](int gq1, int gq0) {
        float2 g10 = gg[gq1][0], g11 = gg[gq1][1], g12 = gg[gq1][2], g13 = gg[gq1][3];
        float2 g00 = gg[gq0][0], g01 = gg[gq0][1], g02 = gg[gq0][2], g03 = gg[gq0][3];
        #pragma unroll
        for (int h = 0; h < 2; ++h) {
            int i0 = (tid + h * 256) << 2;
            float2 v[4]; int sl[4];
            #pragma unroll
            for (int j = 0; j < 4; ++j) { sl[j] = slot2(i0 | j); v[j] = V[sl[j]]; }
            bfly(g10,g11,g12,g13, v[0], v[2]); bfly(g10,g11,g12,g13, v[1], v[3]);
            bfly(g00,g01,g02,g03, v[0], v[1]); bfly(g00,g01,g02,g03, v[2], v[3]);
            #pragma unroll
            for (int j = 0; j < 4; ++j) V[sl[j]] = v[j];
        }
        __syncthreads();
    };

    for (int layer = 1; layer < 5; ++layer) {
        const int gb = layer * 11;
        round3(10, 9, 8, gb + 0, gb + 1, gb + 2, true);   // qubits 0,1,2 (+perm read)
        round3( 7, 6, 5, gb + 3, gb + 4, gb + 5, false);  // qubits 3,4,5
        round3( 4, 3, 2, gb + 6, gb + 7, gb + 8, false);  // qubits 6,7,8
        round2(gb + 9, gb + 10);                          // qubits 9,10
    }
    for (int i = tid; i < DIM; i += 256) {
        float2 v = V[slot2(i)];
        ut_re[(size_t)col*DIM + i] = f2bf(v.x);
        ut_im[(size_t)col*DIM + i] = f2bf(v.y);
    }
}

// ---------------------------------------------------------------------------
// Kernel 2: bf16 transpose (U^T -> U), 64x64 LDS tiles; z selects re/im.
// ---------------------------------------------------------------------------
__global__ __launch_bounds__(256) void transpose2(const u16* __restrict__ sre,
                                                  const u16* __restrict__ sim,
                                                  u16* __restrict__ dre,
                                                  u16* __restrict__ dim_) {
    const u16* s = blockIdx.z ? sim : sre;
    u16*       d = blockIdx.z ? dim_ : dre;
    __shared__ alignas(16) u16 tile[64][66];
    const int bx = blockIdx.x * 64, by = blockIdx.y * 64;
    for (int e = threadIdx.x; e < 1024; e += 256) {
        int r = e >> 4, c4 = (e & 15) * 4;
        uint2 v = *(const uint2*)(s + (size_t)(by + r) * DIM + bx + c4);
        u16* tp = &tile[r][c4];
        tp[0] = (u16)(v.x); tp[1] = (u16)(v.x >> 16);
        tp[2] = (u16)(v.y); tp[3] = (u16)(v.y >> 16);
    }
    __syncthreads();
    for (int e = threadIdx.x; e < 1024; e += 256) {
        int r = e >> 4, c4 = (e & 15) * 4;
        unsigned lo = (unsigned)tile[c4][r]     | ((unsigned)tile[c4+1][r] << 16);
        unsigned hi = (unsigned)tile[c4+2][r]   | ((unsigned)tile[c4+3][r] << 16);
        *(uint2*)(d + (size_t)(bx + r) * DIM + by + c4) = make_uint2(lo, hi);
    }
}

// ---------------------------------------------------------------------------
// Kernel 2b: X (fp32) -> bf16 plane, once. Removes per-z f2bf repack from
// gemm_stage1's staging and halves its global B traffic.
// ---------------------------------------------------------------------------
__global__ __launch_bounds__(256) void x2bf(const float* __restrict__ x,
                                            u16* __restrict__ xb) {
    const int i = (blockIdx.x * 256 + threadIdx.x) * 8;
    const float4* s = (const float4*)(x + i);
    float4 v0 = s[0], v1 = s[1];
    u32x4 pk;
    pk.x = (unsigned)f2bf(v0.x) | ((unsigned)f2bf(v0.y) << 16);
    pk.y = (unsigned)f2bf(v0.z) | ((unsigned)f2bf(v0.w) << 16);
    pk.z = (unsigned)f2bf(v1.x) | ((unsigned)f2bf(v1.y) << 16);
    pk.w = (unsigned)f2bf(v1.z) | ((unsigned)f2bf(v1.w) << 16);
    *(u32x4*)(xb + i) = pk;
}

// ---------------------------------------------------------------------------
// GEMM stage 1 (MFMA, PRODUCT-SPLIT, 128x128, BK=64 two-panel, double-buf):
// z=0: pt = Ure X^T; z=1: qt = Uim X^T.  B now pre-converted bf16 (xb).
// ---------------------------------------------------------------------------
__global__ __launch_bounds__(256, 2) void gemm_stage1(
        const u16* __restrict__ ure, const u16* __restrict__ uim,
        const u16* __restrict__ xb,
        u16* __restrict__ pt, u16* __restrict__ qt) {
    __shared__ alignas(16) u16 Ab[2][2][128*32], Bx[2][2][128*32]; // [buf][panel]
    const u16* A  = blockIdx.z ? uim : ure;
    u16*      dst = blockIdx.z ? qt  : pt;
    const int tid  = threadIdx.x;
    const int lane = tid & 63, w = tid >> 6;
    const int m0 = blockIdx.y * 128, n0 = blockIdx.x * 128;
    const int wm = (w >> 1) * 64, wn = (w & 1) * 64;
    const int ml = lane & 15, quad = lane >> 4;

    f32x4 acc[4][4];
    #pragma unroll
    for (int i = 0; i < 4; ++i)
        #pragma unroll
        for (int j = 0; j < 4; ++j) {
            f32x4 z = {0.f, 0.f, 0.f, 0.f};
            acc[i][j] = z;
        }

    auto stage = [&](int b, int k0) {   // stages both 32-col panels (64 cols)
        #pragma unroll
        for (int pn = 0; pn < 2; ++pn) {
            #pragma unroll
            for (int t = 0; t < 2; ++t) {
                int ci = t * 256 + tid;          // 16B chunk = 8 bf16
                int r = ci >> 2, c = ci & 3;
                size_t goA = ((size_t)(m0 + r) * DIM + k0 + pn * 32) * 2 + c * 16;
                size_t goB = ((size_t)(n0 + r) * DIM + k0 + pn * 32) * 2 + c * 16;
                gl_lds16((const char*)A  + goA, (char*)Ab[b][pn] + ci * 16);
                gl_lds16((const char*)xb + goB, (char*)Bx[b][pn] + ci * 16);
            }
        }
    };

    stage(0, 0);
    __syncthreads();

    for (int k0 = 0; k0 < DIM; k0 += 64) {
        const int cb = (k0 >> 6) & 1;
        if (k0 + 64 < DIM) stage(cb ^ 1, k0 + 64);   // prefetch next 64-col tile

        #pragma unroll
        for (int pn = 0; pn < 2; ++pn) {
            bf16x8 af[4], bf[4];
            #pragma unroll
            for (int i = 0; i < 4; ++i) {
                af[i] = *(const bf16x8*)(Ab[cb][pn] + (wm + i*16 + ml) * 32 + quad * 8);
                bf[i] = *(const bf16x8*)(Bx[cb][pn] + (wn + i*16 + ml) * 32 + quad * 8);
            }
            #pragma unroll
            for (int i = 0; i < 4; ++i)
                #pragma unroll
                for (int j = 0; j < 4; ++j)
                    acc[i][j] = __builtin_amdgcn_mfma_f32_16x16x32_bf16(af[i], bf[j], acc[i][j], 0, 0, 0);
        }
        __syncthreads();
    }
    // C/D layout: col = lane&15, row = quad*4 + reg
    #pragma unroll
    for (int i = 0; i < 4; ++i)
        #pragma unroll
        for (int j = 0; j < 4; ++j) {
            int row = m0 + wm + i*16 + quad*4;
            int col = n0 + wn + j*16 + ml;
            #pragma unroll
            for (int r = 0; r < 4; ++r)
                dst[(size_t)(row + r) * DIM + col] = f2bf(acc[i][j][r]);
        }
}

// ---------------------------------------------------------------------------
// GEMM stage 2 (MFMA, PRODUCT-SPLIT, BK=64 two-panel, fp32 atomics):
// out[m,n] = Ure X Ure^T + Uim X Uim^T = Re(U X U^H).
// ---------------------------------------------------------------------------
__global__ __launch_bounds__(256, 2) void gemm_stage2_atomic(
        const u16* __restrict__ ure, const u16* __restrict__ uim,
        const u16* __restrict__ pt, const u16* __restrict__ qt,
        float* __restrict__ out) {
    __shared__ alignas(16) u16 Ab[2][2][128*32], Bb[2][2][128*32];
    const u16* A = blockIdx.z ? uim : ure;
    const u16* B = blockIdx.z ? qt  : pt;
    const int tid  = threadIdx.x;
    const int lane = tid & 63, w = tid >> 6;
    const int m0 = blockIdx.y * 128, n0 = blockIdx.x * 128;
    const int wm = (w >> 1) * 64, wn = (w & 1) * 64;
    const int ml = lane & 15, quad = lane >> 4;

    f32x4 acc[4][4];
    #pragma unroll
    for (int i = 0; i < 4; ++i)
        #pragma unroll
        for (int j = 0; j < 4; ++j) {
            f32x4 z = {0.f, 0.f, 0.f, 0.f};
            acc[i][j] = z;
        }

    auto stage = [&](int b, int k0) {
        #pragma unroll
        for (int pn = 0; pn < 2; ++pn) {
            #pragma unroll
            for (int t = 0; t < 2; ++t) {
                int ci = t * 256 + tid;
                int r = ci >> 2, c = ci & 3;
                size_t goA = ((size_t)(m0 + r) * DIM + k0 + pn * 32) * 2 + c * 16;
                size_t goB = ((size_t)(n0 + r) * DIM + k0 + pn * 32) * 2 + c * 16;
                gl_lds16((const char*)A + goA, (char*)Ab[b][pn] + ci * 16);
                gl_lds16((const char*)B + goB, (char*)Bb[b][pn] + ci * 16);
            }
        }
    };

    stage(0, 0);
    __syncthreads();

    for (int k0 = 0; k0 < DIM; k0 += 64) {
        const int cb = (k0 >> 6) & 1;
        if (k0 + 64 < DIM) stage(cb ^ 1, k0 + 64);   // prefetch next 64-col tile

        #pragma unroll
        for (int pn = 0; pn < 2; ++pn) {
            bf16x8 af[4], bf[4];
            #pragma unroll
            for (int i = 0; i < 4; ++i) {
                af[i] = *(const bf16x8*)(Ab[cb][pn] + (wm + i*16 + ml) * 32 + quad * 8);
                bf[i] = *(const bf16x8*)(Bb[cb][pn] + (wn + i*16 + ml) * 32 + quad * 8);
            }
            #pragma unroll
            for (int i = 0; i < 4; ++i)
                #pragma unroll
                for (int j = 0; j < 4; ++j)
                    acc[i][j] = __builtin_amdgcn_mfma_f32_16x16x32_bf16(af[i], bf[j], acc[i][j], 0, 0, 0);
        }
        __syncthreads();
    }
    #pragma unroll
    for (int i = 0; i < 4; ++i)
        #pragma unroll
        for (int j = 0; j < 4; ++j) {
            int row = m0 + wm + i*16 + quad*4;
            int col = n0 + wn + j*16 + ml;
            #pragma unroll
            for (int r = 0; r < 4; ++r)
                unsafeAtomicAdd(&out[(size_t)(row + r) * DIM + col], acc[i][j][r]);
        }
}

// ---------------------------------------------------------------------------
// Fallback (complex interleaved output) — insurance only, 128x128 1-buf LDS.
// ---------------------------------------------------------------------------
__global__ __launch_bounds__(256, 1) void gemm_stage2_cplx(
        const u16* __restrict__ ure, const u16* __restrict__ uim,
        const u16* __restrict__ pt, const u16* __restrict__ qt,
        float2* __restrict__ out, size_t out_lim) {
    __shared__ alignas(16) u16 Ar[128*32], Ai[128*32], Bp[128*32], Bq[128*32];
    const int tid  = threadIdx.x;
    const int lane = tid & 63, w = tid >> 6;
    const int m0 = blockIdx.y * 128, n0 = blockIdx.x * 128;
    const int wm = (w >> 1) * 64, wn = (w & 1) * 64;
    const int ml = lane & 15, quad = lane >> 4;

    f32x4 accR[4][4], accI[4][4];
    #pragma unroll
    for (int i = 0; i < 4; ++i)
        #pragma unroll
        for (int j = 0; j < 4; ++j) {
            f32x4 z = {0.f, 0.f, 0.f, 0.f};
            accR[i][j] = z; accI[i][j] = z;
        }

    for (int k0 = 0; k0 < DIM; k0 += 32) {
        #pragma unroll
        for (int t = 0; t < 2; ++t) {
            int ci = t * 256 + tid;
            int r = ci >> 2, c = ci & 3;
            size_t goA = ((size_t)(m0 + r) * DIM + k0) * 2 + c * 16;
            size_t goB = ((size_t)(n0 + r) * DIM + k0) * 2 + c * 16;
            gl_lds16((const char*)ure + goA, (char*)Ar + ci * 16);
            gl_lds16((const char*)uim + goA, (char*)Ai + ci * 16);
            gl_lds16((const char*)pt  + goB, (char*)Bp + ci * 16);
            gl_lds16((const char*)qt  + goB, (char*)Bq + ci * 16);
        }
        __syncthreads();
        bf16x8 ar[4], ai[4], bp[4], bq[4];
        #pragma unroll
        for (int i = 0; i < 4; ++i) {
            ar[i] = *(const bf16x8*)(Ar + (wm + i*16 + ml) * 32 + quad * 8);
            ai[i] = *(const bf16x8*)(Ai + (wm + i*16 + ml) * 32 + quad * 8);
            bp[i] = *(const bf16x8*)(Bp + (wn + i*16 + ml) * 32 + quad * 8);
            bq[i] = *(const bf16x8*)(Bq + (wn + i*16 + ml) * 32 + quad * 8);
        }
        #pragma unroll
        for (int i = 0; i < 4; ++i)
            #pragma unroll
            for (int j = 0; j < 4; ++j) {
                accR[i][j] = __builtin_amdgcn_mfma_f32_16x16x32_bf16(ar[i], bp[j], accR[i][j], 0, 0, 0);
                accR[i][j] = __builtin_amdgcn_mfma_f32_16x16x32_bf16(ai[i], bq[j], accR[i][j], 0, 0, 0);
                accI[i][j] = __builtin_amdgcn_mfma_f32_16x16x32_bf16(ai[i], bp[j], accI[i][j], 0, 0, 0);
                f32x4 t2 = __builtin_amdgcn_mfma_f32_16x16x32_bf16(ar[i], bq[j], {0.f,0.f,0.f,0.f}, 0, 0, 0);
                accI[i][j] -= t2;
            }
        __syncthreads();
    }
    #pragma unroll
    for (int i = 0; i < 4; ++i)
        #pragma unroll
        for (int j = 0; j < 4; ++j) {
            int row = m0 + wm + i*16 + quad*4;
            int col = n0 + wn + j*16 + ml;
            #pragma unroll
            for (int r = 0; r < 4; ++r) {
                size_t idx = (size_t)(row + r) * DIM + col;
                if (idx < out_lim)
                    out[idx] = make_float2(accR[i][j][r], accI[i][j][r]);
            }
        }
}

// ---------------------------------------------------------------------------
extern "C" void kernel_launch(void* const* d_in, const int* in_sizes, int n_in,
                              void* d_out, int out_size, void* d_ws, size_t ws_size,
                              hipStream_t stream) {
    int xi = (in_sizes[0] >= in_sizes[1]) ? 0 : 1;
    const float* x = (const float*)d_in[xi];
    const float* w = (const float*)d_in[1 - xi];

    char* ws = (char*)d_ws;
    const size_t P = (size_t)DIM * DIM * 2;   // one bf16 plane = 8 MiB
    if (ws_size < 4 * P) return;

    u16* ut_re = (u16*)(ws);
    u16* ut_im = (u16*)(ws + P);
    u16* u_re  = (u16*)(ws + 2*P);
    u16* u_im  = (u16*)(ws + 3*P);
    u16* pt    = ut_re;   // reuse after transpose
    u16* qt    = ut_im;
    // bf16 X plane: ws plane 5 if it fits, else d_out's first 8 MiB
    // (d_out is dead until after gemm_stage1 in both output paths).
    u16* xb = (ws_size >= 5 * P) ? (u16*)(ws + 4*P) : (u16*)d_out;

    build_ut<<<DIM, 256, 0, stream>>>(w, ut_re, ut_im);
    transpose2<<<dim3(32, 32, 2), 256, 0, stream>>>(ut_re, ut_im, u_re, u_im);
    x2bf<<<DIM*DIM/(256*8), 256, 0, stream>>>(x, xb);
    gemm_stage1<<<dim3(16, 16, 2), 256, 0, stream>>>(u_re, u_im, xb, pt, qt);

    if (out_size == DIM * DIM) {
        hipMemsetAsync(d_out, 0, (size_t)DIM * DIM * sizeof(float), stream);
        gemm_stage2_atomic<<<dim3(16, 16, 2), 256, 0, stream>>>(u_re, u_im, pt, qt,
                                                                (float*)d_out);
    } else {
        gemm_stage2_cplx<<<dim3(16, 16), 256, 0, stream>>>(u_re, u_im, pt, qt,
                                                           (float2*)d_out,
                                                           (size_t)out_size / 2);
    }
}